// Round 4
// baseline (235.018 us; speedup 1.0000x reference)
//
#include <hip/hip_runtime.h>
#include <hip/hip_bf16.h>
#include <stdint.h>

typedef __bf16 bf16_t;
typedef __attribute__((ext_vector_type(8))) __bf16 bf16x8;
typedef __attribute__((ext_vector_type(4))) __bf16 bf16x4;
typedef __attribute__((ext_vector_type(4))) float f32x4;

static constexpr int T_SEQ = 2048;
static constexpr int HID   = 2048;
static constexpr int NHEAD = 32;
static constexpr int NKVH  = 8;
static constexpr int HDIM  = 64;
static constexpr int QKVD  = 3072;   // 64*(32+16)

__device__ inline f32x4 mfma16(bf16x8 a, bf16x8 b, f32x4 c) {
    return __builtin_amdgcn_mfma_f32_16x16x32_bf16(a, b, c, 0, 0, 0);
}

// async global->LDS DMA: lane i of the wave writes lds_base + i*16 bytes.
__device__ inline void load_lds16(const bf16_t* g, bf16_t* l) {
    __builtin_amdgcn_global_load_lds(
        (const __attribute__((address_space(1))) void*)g,
        (__attribute__((address_space(3))) void*)l, 16, 0, 0);
}

// ---------------- fused transpose+cast of BOTH weights: fp32 [K][N] -> bf16 [N][K] --------
// 64x64 tiles. Phase1: float4 coalesced reads -> LDS (pad 65, scalar stores <=2-way).
// Phase2: 8 scalar LDS reads (bank (8kc+j+n)%32 -> exactly 2-way = free) -> bf16x8
// coalesced 16B stores (8 lanes cover 128B of one output row).
__global__ __launch_bounds__(256) void transpose_both(const float* __restrict__ Wq,
                                                      const float* __restrict__ Wo,
                                                      bf16_t* __restrict__ Tq,
                                                      bf16_t* __restrict__ To) {
    __shared__ float tile[64 * 65];
    int b = blockIdx.x;
    const float* in; bf16_t* out; int NN, KK, bx, by;
    if (b < 1536) { in = Wq; out = Tq; NN = QKVD; KK = HID; bx = b % 48; by = b / 48; }
    else { b -= 1536; in = Wo; out = To; NN = HID; KK = HID; bx = b % 32; by = b / 32; }
    const int t = threadIdx.x;
    const int c4 = (t & 15) * 4;
#pragma unroll
    for (int i = 0; i < 4; ++i) {
        int r = (t >> 4) + i * 16;
        float4 v = *(const float4*)(in + (size_t)(by*64 + r) * NN + bx*64 + c4);
        tile[r*65 + c4 + 0] = v.x; tile[r*65 + c4 + 1] = v.y;
        tile[r*65 + c4 + 2] = v.z; tile[r*65 + c4 + 3] = v.w;
    }
    __syncthreads();
    const int kc = t & 7;
#pragma unroll
    for (int i = 0; i < 2; ++i) {
        int n = (t >> 3) + i * 32;
        bf16x8 o;
#pragma unroll
        for (int j = 0; j < 8; ++j) o[j] = (bf16_t)tile[(kc*8 + j)*65 + n];
        *(bf16x8*)(out + (size_t)(bx*64 + n) * KK + by*64 + kc*8) = o;
    }
}

// ---------------- RMSNorm + cast to bf16 ----------------
__global__ __launch_bounds__(256) void rmsnorm_cast(const float* __restrict__ x,
                                                    const float* __restrict__ scale,
                                                    bf16_t* __restrict__ out) {
    int row = blockIdx.x;
    int tid = threadIdx.x;
    const float4* x4 = (const float4*)(x + (size_t)row * HID);
    const float4* s4 = (const float4*)scale;
    float4 v0 = x4[tid], v1 = x4[tid + 256];
    float ss = v0.x*v0.x + v0.y*v0.y + v0.z*v0.z + v0.w*v0.w
             + v1.x*v1.x + v1.y*v1.y + v1.z*v1.z + v1.w*v1.w;
#pragma unroll
    for (int off = 32; off > 0; off >>= 1) ss += __shfl_down(ss, off);
    __shared__ float wsum[4];
    if ((tid & 63) == 0) wsum[tid >> 6] = ss;
    __syncthreads();
    float total = wsum[0] + wsum[1] + wsum[2] + wsum[3];
    float inv = rsqrtf(total * (1.0f / HID) + 1e-5f);
    float4 sc0 = s4[tid], sc1 = s4[tid + 256];
    bf16_t* outr = out + (size_t)row * HID;
    bf16x4 o0, o1;
    o0.x = (bf16_t)(v0.x*inv*sc0.x); o0.y = (bf16_t)(v0.y*inv*sc0.y);
    o0.z = (bf16_t)(v0.z*inv*sc0.z); o0.w = (bf16_t)(v0.w*inv*sc0.w);
    o1.x = (bf16_t)(v1.x*inv*sc1.x); o1.y = (bf16_t)(v1.y*inv*sc1.y);
    o1.z = (bf16_t)(v1.z*inv*sc1.z); o1.w = (bf16_t)(v1.w*inv*sc1.w);
    *(bf16x4*)(outr + 4*tid)        = o0;
    *(bf16x4*)(outr + 1024 + 4*tid) = o1;
}

// ---------------- split-K GEMM (round-2/3 verified structure) ----------------
__global__ __launch_bounds__(256) void gemm_splitk(const bf16_t* __restrict__ A,
                                                   const bf16_t* __restrict__ Bt,
                                                   bf16_t* __restrict__ Cpart,
                                                   int M, int N, int K) {
    __shared__ __align__(16) bf16_t Asm[128 * 32];
    __shared__ __align__(16) bf16_t Bsm[128 * 32];
    const int tid = threadIdx.x;
    const int bm = blockIdx.y * 128, bn = blockIdx.x * 128;
    const int kh = K >> 1;
    const int kb = blockIdx.z * kh;
    const int lane = tid & 63, wave = tid >> 6;
    const int wm = (wave & 1) * 64, wn = (wave >> 1) * 64;
    const int lm = lane & 15, quad = lane >> 4;

    f32x4 acc[4][4];
#pragma unroll
    for (int i = 0; i < 4; ++i)
#pragma unroll
        for (int j = 0; j < 4; ++j) acc[i][j] = (f32x4){0.f, 0.f, 0.f, 0.f};

    const int cid0 = wave * 64 + lane;
    const int cid1 = cid0 + 256;
    const int r0 = cid0 >> 2, c0 = (cid0 & 3) ^ ((r0 >> 1) & 3);
    const int r1 = cid1 >> 2, c1 = (cid1 & 3) ^ ((r1 >> 1) & 3);
    const bf16_t* Ab = A  + (size_t)bm * K + kb;
    const bf16_t* Bb = Bt + (size_t)bn * K + kb;
    const size_t ga0 = (size_t)r0 * K + c0 * 8;
    const size_t ga1 = (size_t)r1 * K + c1 * 8;
    bf16_t* lds0 = &Asm[wave * 512];
    bf16_t* lds1 = &Asm[2048 + wave * 512];
    bf16_t* ldsB0 = &Bsm[wave * 512];
    bf16_t* ldsB1 = &Bsm[2048 + wave * 512];

    const int swz = (quad ^ ((lm >> 1) & 3)) * 8;

    for (int k0 = 0; k0 < kh; k0 += 32) {
        load_lds16(Ab + ga0 + k0, lds0);
        load_lds16(Ab + ga1 + k0, lds1);
        load_lds16(Bb + ga0 + k0, ldsB0);
        load_lds16(Bb + ga1 + k0, ldsB1);
        __syncthreads();
        bf16x8 af[4], bfr[4];
#pragma unroll
        for (int i = 0; i < 4; ++i)
            af[i]  = *(const bf16x8*)&Asm[(wm + i*16 + lm)*32 + swz];
#pragma unroll
        for (int j = 0; j < 4; ++j)
            bfr[j] = *(const bf16x8*)&Bsm[(wn + j*16 + lm)*32 + swz];
#pragma unroll
        for (int i = 0; i < 4; ++i)
#pragma unroll
            for (int j = 0; j < 4; ++j) acc[i][j] = mfma16(af[i], bfr[j], acc[i][j]);
        __syncthreads();
    }

    bf16_t* Cp = Cpart + (size_t)blockIdx.z * M * N;
#pragma unroll
    for (int i = 0; i < 4; ++i) {
        int gr = bm + wm + i*16 + quad*4;
#pragma unroll
        for (int j = 0; j < 4; ++j) {
            int gc = bn + wn + j*16 + lm;
#pragma unroll
            for (int r = 0; r < 4; ++r)
                Cp[(size_t)(gr + r)*N + gc] = (bf16_t)acc[i][j][r];
        }
    }
}

// ---------------- combine partials + bias + rope (vectorized), scatter to Q/K/V ----------
// 192 threads: tid>>2 = head-row (0..47), tid&3 = 8-elem group in [0,32).
__global__ __launch_bounds__(192) void rope_split(const bf16_t* __restrict__ qp0,
                                                  const bf16_t* __restrict__ qp1,
                                                  const float* __restrict__ qbias,
                                                  const float* __restrict__ cost,
                                                  const float* __restrict__ sint,
                                                  bf16_t* __restrict__ Qb,
                                                  bf16_t* __restrict__ Kb,
                                                  bf16_t* __restrict__ Vb) {
    const int t = blockIdx.x;
    const int hr = threadIdx.x >> 2, p0 = (threadIdx.x & 3) * 8;
    const bf16_t* r0 = qp0 + (size_t)t * QKVD + hr * 64;
    const bf16_t* r1 = qp1 + (size_t)t * QKVD + hr * 64;
    bf16x8 a1 = *(const bf16x8*)(r0 + p0);
    bf16x8 a2 = *(const bf16x8*)(r0 + p0 + 32);
    bf16x8 b1 = *(const bf16x8*)(r1 + p0);
    bf16x8 b2 = *(const bf16x8*)(r1 + p0 + 32);
    const float* qb = qbias + hr * 64;
    float x1[8], x2[8];
#pragma unroll
    for (int j = 0; j < 8; ++j) {
        x1[j] = (float)a1[j] + (float)b1[j] + qb[p0 + j];
        x2[j] = (float)a2[j] + (float)b2[j] + qb[p0 + j + 32];
    }
    bf16x8 w1, w2;
    if (hr < 40) {
        const float* c = cost + (size_t)t * 32 + p0;
        const float* s = sint + (size_t)t * 32 + p0;
#pragma unroll
        for (int j = 0; j < 8; ++j) {
            float cc = c[j], ss = s[j];
            w1[j] = (bf16_t)(x1[j]*cc - x2[j]*ss);
            w2[j] = (bf16_t)(x2[j]*cc + x1[j]*ss);
        }
    } else {
#pragma unroll
        for (int j = 0; j < 8; ++j) { w1[j] = (bf16_t)x1[j]; w2[j] = (bf16_t)x2[j]; }
    }
    bf16_t* dst;
    if (hr < 32)      dst = Qb + ((size_t)t*NHEAD + hr)      * HDIM;
    else if (hr < 40) dst = Kb + ((size_t)t*NKVH + (hr-32))  * HDIM;
    else              dst = Vb + ((size_t)t*NKVH + (hr-40))  * HDIM;
    *(bf16x8*)(dst + p0)      = w1;
    *(bf16x8*)(dst + p0 + 32) = w2;
}

// ---------------- combine out-proj partials + bias + residual ----------------
__global__ __launch_bounds__(256) void combine_out(const bf16_t* __restrict__ p0,
                                                   const bf16_t* __restrict__ p1,
                                                   const float* __restrict__ bias,
                                                   const float* __restrict__ x,
                                                   float* __restrict__ out) {
    const int n4 = T_SEQ * HID / 4;
    for (int i4 = blockIdx.x * 256 + threadIdx.x; i4 < n4; i4 += gridDim.x * 256) {
        bf16x4 a = *(const bf16x4*)(p0 + (size_t)i4 * 4);
        bf16x4 b = *(const bf16x4*)(p1 + (size_t)i4 * 4);
        float4 xv = *(const float4*)(x + (size_t)i4 * 4);
        int col4 = (i4 * 4) & (HID - 1);
        float4 bi = *(const float4*)(bias + col4);
        float4 o;
        o.x = (float)a.x + (float)b.x + bi.x + xv.x;
        o.y = (float)a.y + (float)b.y + bi.y + xv.y;
        o.z = (float)a.z + (float)b.z + bi.z + xv.z;
        o.w = (float)a.w + (float)b.w + bi.w + xv.w;
        *(float4*)(out + (size_t)i4 * 4) = o;
    }
}

// ---------------- attention v2: direct global Q/K fragments, LDS only for V^T and W ------
// One barrier. Negative key rows: address clamped to 0; softmax mask zeroes their weight.
__global__ __launch_bounds__(256) void attn_kernel(const bf16_t* __restrict__ Qb,
                                                   const bf16_t* __restrict__ Kb,
                                                   const bf16_t* __restrict__ Vb,
                                                   const float* __restrict__ sinks,
                                                   bf16_t* __restrict__ attnb) {
    __shared__ __align__(16) bf16_t Vt[64 * 200];   // V^T: [d][k], 25.6 KB
    __shared__ __align__(16) bf16_t Ws[64 * 200];   // P:   [q][k], 25.6 KB

    const int tid = threadIdx.x;
    const int qt = blockIdx.x, h = blockIdx.y;
    const int qs = qt * 64;
    const int nkv = h >> 2;

    // stage V transposed: 768 pair-units (96 key-pairs x 8 offset groups)
#pragma unroll
    for (int it = 0; it < 3; ++it) {
        int pu = tid + it * 256;
        int j = (pu >> 3) * 2, off = (pu & 7) * 8;
        int kg0 = qs - 128 + j; if (kg0 < 0) kg0 = 0;
        int kg1 = qs - 128 + j + 1; if (kg1 < 0) kg1 = 0;
        union { uint4 u; bf16_t e[8]; } v0, v1;
        v0.u = *(const uint4*)(Vb + ((size_t)kg0*NKVH + nkv)*HDIM + off);
        v1.u = *(const uint4*)(Vb + ((size_t)kg1*NKVH + nkv)*HDIM + off);
#pragma unroll
        for (int r = 0; r < 8; ++r) {
            union { uint u; bf16_t e[2]; } p;
            p.e[0] = v0.e[r]; p.e[1] = v1.e[r];
            *(uint*)&Vt[(off + r)*200 + j] = p.u;
        }
    }

    const int lane = tid & 63, wave = tid >> 6;
    const int lm = lane & 15, quad = lane >> 4;
    const int w16 = wave * 16;

    // S = Q K^T : A/B fragments straight from global (k-contiguous 16B loads)
    f32x4 S[12];
#pragma unroll
    for (int jt = 0; jt < 12; ++jt) S[jt] = (f32x4){0.f, 0.f, 0.f, 0.f};
    const bf16_t* Qrow = Qb + ((size_t)(qs + w16 + lm)*NHEAD + h)*HDIM + quad*8;
    int krow[12];
#pragma unroll
    for (int jt = 0; jt < 12; ++jt) {
        int kg = qs - 128 + jt*16 + lm;
        krow[jt] = kg < 0 ? 0 : kg;
    }
#pragma unroll
    for (int ks = 0; ks < 2; ++ks) {
        bf16x8 aq = *(const bf16x8*)(Qrow + ks*32);
#pragma unroll
        for (int jt = 0; jt < 12; ++jt) {
            bf16x8 bk = *(const bf16x8*)(Kb + ((size_t)krow[jt]*NKVH + nkv)*HDIM + ks*32 + quad*8);
            S[jt] = mfma16(aq, bk, S[jt]);
        }
    }

    const float sink = sinks[h];
#pragma unroll
    for (int reg = 0; reg < 4; ++reg) {
        const int qg = qs + w16 + quad*4 + reg;
        float mx = -1e30f;
#pragma unroll
        for (int jt = 0; jt < 12; ++jt) {
            int kg = qs - 128 + jt*16 + lm;
            float sv = S[jt][reg] * 0.125f;
            bool valid = (kg >= 0) && (kg <= qg) && (qg - kg <= 128);
            sv = valid ? sv : -1e30f;
            S[jt][reg] = sv;
            mx = fmaxf(mx, sv);
        }
#pragma unroll
        for (int off = 1; off < 16; off <<= 1) mx = fmaxf(mx, __shfl_xor(mx, off));
        float M = fmaxf(mx, sink);
        float sum = 0.f;
#pragma unroll
        for (int jt = 0; jt < 12; ++jt) {
            float e = __expf(S[jt][reg] - M);
            S[jt][reg] = e; sum += e;
        }
#pragma unroll
        for (int off = 1; off < 16; off <<= 1) sum += __shfl_xor(sum, off);
        float rden = 1.f / (sum + __expf(sink - M));
#pragma unroll
        for (int jt = 0; jt < 12; ++jt)
            Ws[(w16 + quad*4 + reg)*200 + jt*16 + lm] = (bf16_t)(S[jt][reg] * rden);
    }
    __syncthreads();   // V staging + Ws writes complete

    // O = W V
    f32x4 O[4];
#pragma unroll
    for (int nt = 0; nt < 4; ++nt) O[nt] = (f32x4){0.f, 0.f, 0.f, 0.f};
#pragma unroll
    for (int ks = 0; ks < 6; ++ks) {
        bf16x8 aw = *(const bf16x8*)&Ws[(w16 + lm)*200 + ks*32 + quad*8];
#pragma unroll
        for (int nt = 0; nt < 4; ++nt) {
            bf16x8 bv = *(const bf16x8*)&Vt[(nt*16 + lm)*200 + ks*32 + quad*8];
            O[nt] = mfma16(aw, bv, O[nt]);
        }
    }
#pragma unroll
    for (int nt = 0; nt < 4; ++nt)
#pragma unroll
        for (int reg = 0; reg < 4; ++reg)
            attnb[(size_t)(qs + w16 + quad*4 + reg)*HID + h*HDIM + nt*16 + lm] =
                (bf16_t)(O[nt][reg]);
}

// ---------------- launch ----------------
extern "C" void kernel_launch(void* const* d_in, const int* in_sizes, int n_in,
                              void* d_out, int out_size, void* d_ws, size_t ws_size,
                              hipStream_t stream) {
    (void)in_sizes; (void)n_in; (void)out_size; (void)ws_size;
    const float* x          = (const float*)d_in[0];
    const float* scale      = (const float*)d_in[1];
    const float* sinks      = (const float*)d_in[2];
    const float* qkv_kernel = (const float*)d_in[3];
    const float* qkv_bias   = (const float*)d_in[4];
    const float* out_kernel = (const float*)d_in[5];
    const float* out_bias   = (const float*)d_in[6];
    const float* cos_t      = (const float*)d_in[7];
    const float* sin_t      = (const float*)d_in[8];
    float* out = (float*)d_out;

    // ws plan (64 MiB, aliasing by liveness) — unchanged from round 3
    char* ws = (char*)d_ws;
    const size_t MiB = 1048576;
    bf16_t* Wt_out = (bf16_t*)(ws);
    bf16_t* Wt_qkv = (bf16_t*)(ws + 8*MiB);
    bf16_t* attnb  = (bf16_t*)(ws + 8*MiB);
    bf16_t* normed = (bf16_t*)(ws + 20*MiB);
    bf16_t* qkvp   = (bf16_t*)(ws + 28*MiB);
    bf16_t* outp   = (bf16_t*)(ws + 28*MiB);
    bf16_t* Qb     = (bf16_t*)(ws + 52*MiB);
    bf16_t* Kb     = (bf16_t*)(ws + 60*MiB);
    bf16_t* Vb     = (bf16_t*)(ws + 62*MiB);

    transpose_both<<<2560, 256, 0, stream>>>(qkv_kernel, out_kernel, Wt_qkv, Wt_out);
    rmsnorm_cast<<<T_SEQ, 256, 0, stream>>>(x, scale, normed);
    gemm_splitk<<<dim3(QKVD/128, T_SEQ/128, 2), 256, 0, stream>>>(normed, Wt_qkv, qkvp,
                                                                  T_SEQ, QKVD, HID);
    rope_split<<<T_SEQ, 192, 0, stream>>>(qkvp, qkvp + (size_t)T_SEQ*QKVD, qkv_bias,
                                          cos_t, sin_t, Qb, Kb, Vb);
    attn_kernel<<<dim3(T_SEQ/64, NHEAD), 256, 0, stream>>>(Qb, Kb, Vb, sinks, attnb);
    gemm_splitk<<<dim3(HID/128, T_SEQ/128, 2), 256, 0, stream>>>(attnb, Wt_out, outp,
                                                                 T_SEQ, HID, HID);
    combine_out<<<2048, 256, 0, stream>>>(outp, outp + (size_t)T_SEQ*HID, out_bias, x, out);
}